// Round 2
// baseline (731.288 us; speedup 1.0000x reference)
//
#include <hip/hip_runtime.h>
#include <hip/hip_bf16.h>

// DomainSpecificHeads: out[b] = (hs[b] @ W_base + b_base) @ W_heads[idx[b]] + b_heads[idx[b]]
// B=8 S=512 D=1024 V=32000 ND=8 (slot ND = default head for out-of-range ids)

#define BCNT 8
#define SLEN 512
#define DDIM 1024
#define VDIM 32000
#define NDOM 8

typedef __attribute__((ext_vector_type(4))) float f32x4;
typedef __attribute__((ext_vector_type(8))) short bf16x8;

static __device__ __forceinline__ unsigned short f2bf(float f) {
    union { float f; unsigned int u; } x; x.f = f;
    unsigned int u = x.u;
    return (unsigned short)((u + 0x7FFFu + ((u >> 16) & 1u)) >> 16);  // RNE
}

static __device__ __forceinline__ unsigned int pack2(float lo, float hi) {
    return (unsigned int)f2bf(lo) | ((unsigned int)f2bf(hi) << 16);
}

// ---------------- G1: hidden = hs @ W_base + b_base  (fp32 in, bf16 out) ----------------
// 128x128 tile, BK=64, 256 threads, 2x2 waves (validated round-1 structure, unchanged).
__global__ __launch_bounds__(256)
void gemm1_k(const float* __restrict__ Af, const float* __restrict__ Bbase,
             const float* __restrict__ bias, __hip_bfloat16* __restrict__ Cb,
             int Mrows)
{
    __shared__ __align__(16) __hip_bfloat16 lds_a[128 * 64];
    __shared__ __align__(16) unsigned int   lds_b[32 * 128];

    const int tid  = threadIdx.x;
    const int lane = tid & 63;
    const int w    = tid >> 6;

    const int nwg = gridDim.x;
    const int bid = blockIdx.x;
    const int q   = nwg >> 3;
    const int sid = (bid & 7) * q + (bid >> 3);

    const int MT = Mrows >> 7;
    const int mt = sid % MT;
    const int nt = sid / MT;
    const int m0 = mt << 7;
    const int n0 = nt << 7;

    f32x4 acc[4][4];
    #pragma unroll
    for (int m = 0; m < 4; ++m)
        #pragma unroll
        for (int n = 0; n < 4; ++n)
            acc[m][n] = (f32x4)0.0f;

    const int wr = w >> 1, wc = w & 1;
    const int lr = lane & 15, lg = lane >> 4;

    for (int kt = 0; kt < DDIM / 64; ++kt) {
        const int kbase = kt * 64;

        #pragma unroll
        for (int t = 0; t < 8; ++t) {
            const int flat = (t * 256 + tid) * 4;
            const int row = flat >> 6, col = flat & 63;
            const float4 v = *(const float4*)(Af + (size_t)(m0 + row) * DDIM + kbase + col);
            uint2 pp;
            pp.x = pack2(v.x, v.y);
            pp.y = pack2(v.z, v.w);
            *(uint2*)(lds_a + flat) = pp;
        }

        #pragma unroll
        for (int t = 0; t < 4; ++t) {
            const int id = t * 256 + tid;
            const int kk = id >> 5;
            const int n  = (id & 31) << 2;
            const float* b0 = Bbase + (size_t)(kbase + 2 * kk) * DDIM + n0 + n;
            const float4 e = *(const float4*)b0;
            const float4 o = *(const float4*)(b0 + DDIM);
            uint4 pw;
            pw.x = pack2(e.x, o.x);
            pw.y = pack2(e.y, o.y);
            pw.z = pack2(e.z, o.z);
            pw.w = pack2(e.w, o.w);
            const int ns = n ^ ((kk & 4) << 2);
            *(uint4*)&lds_b[kk * 128 + ns] = pw;
        }

        __syncthreads();

        #pragma unroll
        for (int ks = 0; ks < 2; ++ks) {
            bf16x8 af[4], bfr[4];
            #pragma unroll
            for (int m = 0; m < 4; ++m) {
                const int row = wr * 64 + m * 16 + lr;
                const int k   = ks * 32 + lg * 8;
                af[m] = *(const bf16x8*)&lds_a[row * 64 + k];
            }
            #pragma unroll
            for (int n = 0; n < 4; ++n) {
                const int col = wc * 64 + n * 16 + lr;
                const int kkb = ks * 16 + lg * 4;
                union { unsigned int u[4]; bf16x8 v; } cvt;
                #pragma unroll
                for (int j = 0; j < 4; ++j) {
                    const int kk = kkb + j;
                    const int ns = col ^ ((kk & 4) << 2);
                    cvt.u[j] = lds_b[kk * 128 + ns];
                }
                bfr[n] = cvt.v;
            }
            #pragma unroll
            for (int m = 0; m < 4; ++m)
                #pragma unroll
                for (int n = 0; n < 4; ++n)
                    acc[m][n] = __builtin_amdgcn_mfma_f32_16x16x32_bf16(af[m], bfr[n], acc[m][n], 0, 0, 0);
        }

        __syncthreads();
    }

    #pragma unroll
    for (int m = 0; m < 4; ++m) {
        #pragma unroll
        for (int n = 0; n < 4; ++n) {
            const int col = n0 + wc * 64 + n * 16 + lr;
            const float bv = bias[col];
            #pragma unroll
            for (int r = 0; r < 4; ++r) {
                const int row = m0 + wr * 64 + m * 16 + lg * 4 + r;
                Cb[(size_t)row * DDIM + col] = __hip_bfloat16_raw{f2bf(acc[m][n][r] + bv)};
            }
        }
    }
}

// ---------------- G2: out = hidden @ W_heads[idx] + b_heads[idx] ----------------
// BM=256 BN=128 BK=64, 512 threads (8 waves, 4x2 grid of 64x64 wave tiles).
// A (bf16) via global_load_lds (linear LDS). B (fp32) reg-staged -> bf16 k-pair u32,
// stored TRANSPOSED [n][kk] with XOR swizzle so fragment reads are ds_read_b128.
__global__ __launch_bounds__(512)
void gemm2_k(const __hip_bfloat16* __restrict__ A, const float* __restrict__ Wh,
             const float* __restrict__ bh, float* __restrict__ out,
             const int* __restrict__ dom)
{
    __shared__ __align__(16) __hip_bfloat16 lds_a[256 * 64];    // 32 KB
    __shared__ __align__(16) unsigned int   lds_bt[128 * 32];   // 16 KB, [n][kk] u32 pairs

    const int tid  = threadIdx.x;
    const int lane = tid & 63;
    const int w    = tid >> 6;      // 0..7
    const int wr   = w >> 1;        // 0..3 -> 64-row stripe
    const int wc   = w & 1;         // 0..1 -> 64-col stripe
    const int lr   = lane & 15;
    const int lg   = lane >> 4;

    // XCD-chunked swizzle; grid = 4000 (%8==0). Work order: mt innermost (panel pair),
    // nt next, ex outermost -> each XCD streams one example's head through its L2.
    const int bid = blockIdx.x;
    const int q   = gridDim.x >> 3;              // 500
    const int sid = (bid & 7) * q + (bid >> 3);
    const int mt   = sid & 1;
    const int rest = sid >> 1;
    const int nt   = rest % 250;
    const int ex   = rest / 250;
    const int m0   = ex * SLEN + mt * 256;
    const int n0   = nt * 128;

    const int di  = dom[ex];
    const int hid = (di >= 0 && di < NDOM) ? di : NDOM;
    const float* Bp   = Wh + (size_t)hid * DDIM * (size_t)VDIM;
    const float* bias = bh + (size_t)hid * (size_t)VDIM;

    f32x4 acc[4][4];
    #pragma unroll
    for (int m = 0; m < 4; ++m)
        #pragma unroll
        for (int n = 0; n < 4; ++n)
            acc[m][n] = (f32x4)0.0f;

    // B staging geometry: tile 64k x 128n fp32 -> 32 kk-pairs x 128 n (4096 u32).
    // Two chunks per thread: (kk0, n40..+3) and (kk1, n41..+3).
    const int kk0 = tid >> 5;            // 0..15
    const int n40 = (tid & 31) << 2;
    const int kk1 = 16 + kk0;            // 16..31
    const int n41 = n40;
    const int swz0 = ((n40 >> 2) & 7) << 2;   // == ((tid&7)<<2)

    float4 e0, o0, e1, o1;

    // prologue: load B regs for kt=0
    {
        const float* p0 = Bp + (size_t)(2 * kk0) * VDIM + n0 + n40;
        e0 = *(const float4*)p0;  o0 = *(const float4*)(p0 + VDIM);
        const float* p1 = Bp + (size_t)(2 * kk1) * VDIM + n0 + n41;
        e1 = *(const float4*)p1;  o1 = *(const float4*)(p1 + VDIM);
    }

    for (int kt = 0; kt < DDIM / 64; ++kt) {
        const int kbase = kt * 64;

        // ---- A: async global -> LDS (linear), 4 insts per wave ----
        #pragma unroll
        for (int i = 0; i < 4; ++i) {
            const int base_e = (i * 8 + w) * 512;        // wave-uniform LDS base (elems)
            const int flat   = base_e + lane * 8;
            const int row = flat >> 6, col = flat & 63;
            const __hip_bfloat16* src = A + (size_t)(m0 + row) * DDIM + kbase + col;
            __builtin_amdgcn_global_load_lds(
                (const __attribute__((address_space(1))) unsigned int*)src,
                (__attribute__((address_space(3))) unsigned int*)(lds_a + base_e),
                16, 0, 0);
        }

        // ---- B: convert regs -> transposed swizzled LDS ----
        {
            unsigned int p[4];
            p[0] = pack2(e0.x, o0.x); p[1] = pack2(e0.y, o0.y);
            p[2] = pack2(e0.z, o0.z); p[3] = pack2(e0.w, o0.w);
            const int ks0 = kk0 ^ swz0;
            #pragma unroll
            for (int i = 0; i < 4; ++i) lds_bt[(n40 + i) * 32 + ks0] = p[i];
            p[0] = pack2(e1.x, o1.x); p[1] = pack2(e1.y, o1.y);
            p[2] = pack2(e1.z, o1.z); p[3] = pack2(e1.w, o1.w);
            const int ks1 = kk1 ^ swz0;
            #pragma unroll
            for (int i = 0; i < 4; ++i) lds_bt[(n41 + i) * 32 + ks1] = p[i];
        }

        __syncthreads();

        // ---- prefetch next B tile into regs (hides HBM latency under MFMA) ----
        if (kt + 1 < DDIM / 64) {
            const int kb = kbase + 64;
            const float* p0 = Bp + (size_t)(kb + 2 * kk0) * VDIM + n0 + n40;
            e0 = *(const float4*)p0;  o0 = *(const float4*)(p0 + VDIM);
            const float* p1 = Bp + (size_t)(kb + 2 * kk1) * VDIM + n0 + n41;
            e1 = *(const float4*)p1;  o1 = *(const float4*)(p1 + VDIM);
        }

        // ---- compute ----
        #pragma unroll
        for (int ks = 0; ks < 2; ++ks) {
            bf16x8 af[4], bfr[4];
            #pragma unroll
            for (int m = 0; m < 4; ++m) {
                const int row = wr * 64 + m * 16 + lr;
                const int k   = ks * 32 + lg * 8;
                af[m] = *(const bf16x8*)&lds_a[row * 64 + k];
            }
            #pragma unroll
            for (int n = 0; n < 4; ++n) {
                const int col  = wc * 64 + n * 16 + lr;
                const int kkb  = ks * 16 + lg * 4;
                const int swzc = ((col >> 2) & 7) << 2;
                bfr[n] = *(const bf16x8*)&lds_bt[col * 32 + (kkb ^ swzc)];
            }
            #pragma unroll
            for (int m = 0; m < 4; ++m)
                #pragma unroll
                for (int n = 0; n < 4; ++n)
                    acc[m][n] = __builtin_amdgcn_mfma_f32_16x16x32_bf16(af[m], bfr[n], acc[m][n], 0, 0, 0);
        }

        __syncthreads();
    }

    // ---- epilogue ----
    #pragma unroll
    for (int n = 0; n < 4; ++n) {
        const int col = n0 + wc * 64 + n * 16 + lr;
        const float bv = bias[col];
        #pragma unroll
        for (int m = 0; m < 4; ++m) {
            #pragma unroll
            for (int r = 0; r < 4; ++r) {
                const int row = m0 + wr * 64 + m * 16 + lg * 4 + r;
                out[(size_t)row * VDIM + col] = acc[m][n][r] + bv;
            }
        }
    }
}

extern "C" void kernel_launch(void* const* d_in, const int* in_sizes, int n_in,
                              void* d_out, int out_size, void* d_ws, size_t ws_size,
                              hipStream_t stream)
{
    const float* hs  = (const float*)d_in[0];   // [8,512,1024] fp32
    const int*   dom = (const int*)d_in[1];     // [8] int32
    const float* Wb  = (const float*)d_in[2];   // [1024,1024] fp32
    const float* bb  = (const float*)d_in[3];   // [1024] fp32
    const float* Wh  = (const float*)d_in[4];   // [9,1024,32000] fp32
    const float* bh  = (const float*)d_in[5];   // [9,32000] fp32
    float* out = (float*)d_out;                 // [8,512,32000] fp32
    __hip_bfloat16* hidden = (__hip_bfloat16*)d_ws;   // [4096,1024] bf16, 8 MB

    const int M = BCNT * SLEN;  // 4096

    // G1: 256 blocks of 256 threads
    const int g1 = (M / 128) * (DDIM / 128);
    hipLaunchKernelGGL(gemm1_k, dim3(g1), dim3(256), 0, stream, hs, Wb, bb, hidden, M);

    // G2: 8 ex * 2 mt * 250 nt = 4000 blocks of 512 threads
    const int g2 = BCNT * (SLEN / 256) * (VDIM / 128);
    hipLaunchKernelGGL(gemm2_k, dim3(g2), dim3(512), 0, stream, hidden, Wh, bh, out, dom);
}

// Round 3
// 658.449 us; speedup vs baseline: 1.1106x; 1.1106x over previous
//
#include <hip/hip_runtime.h>
#include <hip/hip_bf16.h>

// DomainSpecificHeads: out[b] = (hs[b] @ W_base + b_base) @ W_heads[idx[b]] + b_heads[idx[b]]
// B=8 S=512 D=1024 V=32000 ND=8 (slot ND = default head for out-of-range ids)

#define BCNT 8
#define SLEN 512
#define DDIM 1024
#define VDIM 32000
#define NDOM 8

typedef __attribute__((ext_vector_type(4))) float f32x4;
typedef __attribute__((ext_vector_type(8))) short bf16x8;

static __device__ __forceinline__ unsigned short f2bf(float f) {
    union { float f; unsigned int u; } x; x.f = f;
    unsigned int u = x.u;
    return (unsigned short)((u + 0x7FFFu + ((u >> 16) & 1u)) >> 16);  // RNE
}

static __device__ __forceinline__ unsigned int pack2(float lo, float hi) {
    return (unsigned int)f2bf(lo) | ((unsigned int)f2bf(hi) << 16);
}

#define SBAR()   __builtin_amdgcn_s_barrier()
#define SCHED0() __builtin_amdgcn_sched_barrier(0)

// ---------------- G1: hidden = hs @ W_base + b_base  (fp32 in, bf16 out) ----------------
// 128x128 tile, BK=64, 256 threads, 2x2 waves (validated round-1 structure, unchanged).
__global__ __launch_bounds__(256)
void gemm1_k(const float* __restrict__ Af, const float* __restrict__ Bbase,
             const float* __restrict__ bias, __hip_bfloat16* __restrict__ Cb,
             int Mrows)
{
    __shared__ __align__(16) __hip_bfloat16 lds_a[128 * 64];
    __shared__ __align__(16) unsigned int   lds_b[32 * 128];

    const int tid  = threadIdx.x;
    const int lane = tid & 63;
    const int w    = tid >> 6;

    const int nwg = gridDim.x;
    const int bid = blockIdx.x;
    const int q   = nwg >> 3;
    const int sid = (bid & 7) * q + (bid >> 3);

    const int MT = Mrows >> 7;
    const int mt = sid % MT;
    const int nt = sid / MT;
    const int m0 = mt << 7;
    const int n0 = nt << 7;

    f32x4 acc[4][4];
    #pragma unroll
    for (int m = 0; m < 4; ++m)
        #pragma unroll
        for (int n = 0; n < 4; ++n)
            acc[m][n] = (f32x4)0.0f;

    const int wr = w >> 1, wc = w & 1;
    const int lr = lane & 15, lg = lane >> 4;

    for (int kt = 0; kt < DDIM / 64; ++kt) {
        const int kbase = kt * 64;

        #pragma unroll
        for (int t = 0; t < 8; ++t) {
            const int flat = (t * 256 + tid) * 4;
            const int row = flat >> 6, col = flat & 63;
            const float4 v = *(const float4*)(Af + (size_t)(m0 + row) * DDIM + kbase + col);
            uint2 pp;
            pp.x = pack2(v.x, v.y);
            pp.y = pack2(v.z, v.w);
            *(uint2*)(lds_a + flat) = pp;
        }

        #pragma unroll
        for (int t = 0; t < 4; ++t) {
            const int id = t * 256 + tid;
            const int kk = id >> 5;
            const int n  = (id & 31) << 2;
            const float* b0 = Bbase + (size_t)(kbase + 2 * kk) * DDIM + n0 + n;
            const float4 e = *(const float4*)b0;
            const float4 o = *(const float4*)(b0 + DDIM);
            uint4 pw;
            pw.x = pack2(e.x, o.x);
            pw.y = pack2(e.y, o.y);
            pw.z = pack2(e.z, o.z);
            pw.w = pack2(e.w, o.w);
            const int ns = n ^ ((kk & 4) << 2);
            *(uint4*)&lds_b[kk * 128 + ns] = pw;
        }

        __syncthreads();

        #pragma unroll
        for (int ks = 0; ks < 2; ++ks) {
            bf16x8 af[4], bfr[4];
            #pragma unroll
            for (int m = 0; m < 4; ++m) {
                const int row = wr * 64 + m * 16 + lr;
                const int k   = ks * 32 + lg * 8;
                af[m] = *(const bf16x8*)&lds_a[row * 64 + k];
            }
            #pragma unroll
            for (int n = 0; n < 4; ++n) {
                const int col = wc * 64 + n * 16 + lr;
                const int kkb = ks * 16 + lg * 4;
                union { unsigned int u[4]; bf16x8 v; } cvt;
                #pragma unroll
                for (int j = 0; j < 4; ++j) {
                    const int kk = kkb + j;
                    const int ns = col ^ ((kk & 4) << 2);
                    cvt.u[j] = lds_b[kk * 128 + ns];
                }
                bfr[n] = cvt.v;
            }
            #pragma unroll
            for (int m = 0; m < 4; ++m)
                #pragma unroll
                for (int n = 0; n < 4; ++n)
                    acc[m][n] = __builtin_amdgcn_mfma_f32_16x16x32_bf16(af[m], bfr[n], acc[m][n], 0, 0, 0);
        }

        __syncthreads();
    }

    #pragma unroll
    for (int m = 0; m < 4; ++m) {
        #pragma unroll
        for (int n = 0; n < 4; ++n) {
            const int col = n0 + wc * 64 + n * 16 + lr;
            const float bv = bias[col];
            #pragma unroll
            for (int r = 0; r < 4; ++r) {
                const int row = m0 + wr * 64 + m * 16 + lg * 4 + r;
                Cb[(size_t)row * DDIM + col] = __hip_bfloat16_raw{f2bf(acc[m][n][r] + bv)};
            }
        }
    }
}

// ---------------- G2: out = hidden @ W_heads[idx] + b_heads[idx] ----------------
// BM=256 BN=128 BK=64, 512 threads (8 waves, 4x2 grid of 64x64 wave tiles).
// Double-buffered (96 KB dynamic LDS), ONE barrier per K-step, counted vmcnt(8).
// A: global_load_lds with PRE-SWIZZLED source (kbyte ^= (row&7)<<4), same XOR on read.
// B: fp32 float2 loads (8 k-rows x 2 n per thread) -> packed kk-quads, b128 writes,
//    slot swizzle kk ^ ((n>>1)&7)<<2 -> 8 quads x 8 lanes on write AND read (conflict-free).
__global__ __launch_bounds__(512)
void gemm2_k(const __hip_bfloat16* __restrict__ A, const float* __restrict__ Wh,
             const float* __restrict__ bh, float* __restrict__ out,
             const int* __restrict__ dom)
{
    extern __shared__ __align__(16) char smem[];
    __hip_bfloat16* ldsA0 = (__hip_bfloat16*)smem;                    // 32 KB
    __hip_bfloat16* ldsA1 = (__hip_bfloat16*)(smem + 32768);          // 32 KB
    unsigned int*   ldsB0 = (unsigned int*)(smem + 65536);            // 16 KB
    unsigned int*   ldsB1 = (unsigned int*)(smem + 65536 + 16384);    // 16 KB

    const int tid  = threadIdx.x;
    const int lane = tid & 63;
    const int w    = tid >> 6;      // 0..7
    const int wr   = w >> 1;        // 0..3 -> 64-row stripe
    const int wc   = w & 1;         // 0..1 -> 64-col stripe
    const int lr   = lane & 15;
    const int lg   = lane >> 4;

    // XCD-chunked swizzle; grid = 4000 (%8==0). Decomposition puts each example
    // (= one head, streamed) on exactly one XCD's L2; mt innermost shares the W panel.
    const int bid = blockIdx.x;
    const int q   = gridDim.x >> 3;              // 500
    const int sid = (bid & 7) * q + (bid >> 3);
    const int mt   = sid & 1;
    const int rest = sid >> 1;
    const int nt   = rest % 250;
    const int ex   = rest / 250;
    const int m0   = ex * SLEN + mt * 256;
    const int n0   = nt * 128;

    const int di  = dom[ex];
    const int hid = (di >= 0 && di < NDOM) ? di : NDOM;
    const float* Bp   = Wh + (size_t)hid * DDIM * (size_t)VDIM;
    const float* bias = bh + (size_t)hid * (size_t)VDIM;

    f32x4 acc[4][4];
    #pragma unroll
    for (int m = 0; m < 4; ++m)
        #pragma unroll
        for (int n = 0; n < 4; ++n)
            acc[m][n] = (f32x4)0.0f;

    // ---- B staging assignment: thread owns 8 k-rows x 2 cols ----
    const int nb   = (tid & 63) * 2;          // n pair base: 0..126
    const int kb   = (tid >> 6) * 8;          // 8 k-rows per wave
    const int bswz = (lane & 7) << 2;         // == ((nb>>1)&7)<<2
    const int bslot = ((kb >> 1) ^ bswz);     // kk-quad slot, multiple of 4

    float2 br[8];

    #define LOADB(KT) do {                                                        \
        const float* _p = Bp + (size_t)((KT) * 64 + kb) * VDIM + n0 + nb;         \
        _Pragma("unroll")                                                         \
        for (int j = 0; j < 8; ++j) br[j] = *(const float2*)(_p + (size_t)j * VDIM); \
    } while (0)

    #define WRITEB(LB) do {                                                       \
        uint4 w0, w1;                                                             \
        w0.x = pack2(br[0].x, br[1].x); w0.y = pack2(br[2].x, br[3].x);           \
        w0.z = pack2(br[4].x, br[5].x); w0.w = pack2(br[6].x, br[7].x);           \
        w1.x = pack2(br[0].y, br[1].y); w1.y = pack2(br[2].y, br[3].y);           \
        w1.z = pack2(br[4].y, br[5].y); w1.w = pack2(br[6].y, br[7].y);           \
        *(uint4*)&(LB)[nb * 32 + bslot]       = w0;                               \
        *(uint4*)&(LB)[(nb + 1) * 32 + bslot] = w1;                               \
    } while (0)

    #define STAGEA(LA, KT) do {                                                   \
        _Pragma("unroll")                                                         \
        for (int i = 0; i < 4; ++i) {                                             \
            const int base_e = (i * 8 + w) * 512;                                 \
            const int flat   = base_e + lane * 8;                                 \
            const int row    = flat >> 6;                                         \
            const int kbyte  = (flat & 63) * 2;                                   \
            const int srck   = (kbyte ^ ((row & 7) << 4)) >> 1;                   \
            const __hip_bfloat16* src = A + (size_t)(m0 + row) * DDIM + (KT) * 64 + srck; \
            __builtin_amdgcn_global_load_lds(                                     \
                (const __attribute__((address_space(1))) unsigned int*)src,       \
                (__attribute__((address_space(3))) unsigned int*)((LA) + base_e), \
                16, 0, 0);                                                        \
        }                                                                         \
    } while (0)

    #define COMPUTE(LA, LB) do {                                                  \
        _Pragma("unroll")                                                         \
        for (int ks = 0; ks < 2; ++ks) {                                          \
            bf16x8 af[4], bfr[4];                                                 \
            _Pragma("unroll")                                                     \
            for (int m = 0; m < 4; ++m) {                                         \
                const int row = wr * 64 + m * 16 + lr;                            \
                const int kby = ks * 64 + lg * 16;                                \
                const int eff = kby ^ ((row & 7) << 4);                           \
                af[m] = *(const bf16x8*)&(LA)[row * 64 + (eff >> 1)];             \
            }                                                                     \
            _Pragma("unroll")                                                     \
            for (int n = 0; n < 4; ++n) {                                         \
                const int col  = wc * 64 + n * 16 + lr;                           \
                const int kkb  = ks * 16 + lg * 4;                                \
                const int slot = kkb ^ (((col >> 1) & 7) << 2);                   \
                bfr[n] = *(const bf16x8*)&(LB)[col * 32 + slot];                  \
            }                                                                     \
            _Pragma("unroll")                                                     \
            for (int m = 0; m < 4; ++m)                                           \
                _Pragma("unroll")                                                 \
                for (int n = 0; n < 4; ++n)                                       \
                    acc[m][n] = __builtin_amdgcn_mfma_f32_16x16x32_bf16(af[m], bfr[n], acc[m][n], 0, 0, 0); \
        }                                                                         \
    } while (0)

    // ---- prologue: fill buffer 0, start B(1) ----
    LOADB(0);
    STAGEA(ldsA0, 0);
    SCHED0();
    WRITEB(ldsB0);          // consumes br(0); compiler inserts counted vmcnt for it
    LOADB(1);
    SCHED0();
    asm volatile("s_waitcnt vmcnt(8) lgkmcnt(0)" ::: "memory");  // A(0)+writes done; B(1) in flight
    SCHED0();
    SBAR();

    // ---- main loop: one barrier per K-step ----
    for (int kt = 0; kt < 16; ++kt) {
        __hip_bfloat16* la = (kt & 1) ? ldsA1 : ldsA0;
        __hip_bfloat16* ln = (kt & 1) ? ldsA0 : ldsA1;
        unsigned int*   lb = (kt & 1) ? ldsB1 : ldsB0;
        unsigned int*   lnb = (kt & 1) ? ldsB0 : ldsB1;

        if (kt < 15) {
            STAGEA(ln, kt + 1);          // 4x global_load_lds into the idle buffer
            SCHED0();
            WRITEB(lnb);                 // br holds B(kt+1)
            if (kt < 14) LOADB(kt + 2);  // 8 loads stay in flight across the barrier
            SCHED0();
        }

        COMPUTE(la, lb);

        if (kt < 15) {
            SCHED0();
            if (kt < 14) asm volatile("s_waitcnt vmcnt(8) lgkmcnt(0)" ::: "memory");
            else         asm volatile("s_waitcnt vmcnt(0) lgkmcnt(0)" ::: "memory");
            SCHED0();
            SBAR();
        }
    }

    // ---- epilogue ----
    #pragma unroll
    for (int n = 0; n < 4; ++n) {
        const int col = n0 + wc * 64 + n * 16 + lr;
        const float bv = bias[col];
        #pragma unroll
        for (int m = 0; m < 4; ++m) {
            #pragma unroll
            for (int r = 0; r < 4; ++r) {
                const int row = m0 + wr * 64 + m * 16 + lg * 4 + r;
                out[(size_t)row * VDIM + col] = acc[m][n][r] + bv;
            }
        }
    }

    #undef LOADB
    #undef WRITEB
    #undef STAGEA
    #undef COMPUTE
}

extern "C" void kernel_launch(void* const* d_in, const int* in_sizes, int n_in,
                              void* d_out, int out_size, void* d_ws, size_t ws_size,
                              hipStream_t stream)
{
    const float* hs  = (const float*)d_in[0];   // [8,512,1024] fp32
    const int*   dom = (const int*)d_in[1];     // [8] int32
    const float* Wb  = (const float*)d_in[2];   // [1024,1024] fp32
    const float* bb  = (const float*)d_in[3];   // [1024] fp32
    const float* Wh  = (const float*)d_in[4];   // [9,1024,32000] fp32
    const float* bh  = (const float*)d_in[5];   // [9,32000] fp32
    float* out = (float*)d_out;                 // [8,512,32000] fp32
    __hip_bfloat16* hidden = (__hip_bfloat16*)d_ws;   // [4096,1024] bf16, 8 MB

    const int M = BCNT * SLEN;  // 4096

    // G1: 256 blocks of 256 threads
    const int g1 = (M / 128) * (DDIM / 128);
    hipLaunchKernelGGL(gemm1_k, dim3(g1), dim3(256), 0, stream, hs, Wb, bb, hidden, M);

    // G2: 8 ex * 2 mt * 250 nt = 4000 blocks of 512 threads, 96 KB dynamic LDS
    const int smem_bytes = 98304;
    static int attr_set = 0;
    if (!attr_set) {  // host-side attribute, deterministic, not a stream op
        hipFuncSetAttribute((const void*)gemm2_k, hipFuncAttributeMaxDynamicSharedMemorySize, smem_bytes);
        attr_set = 1;
    }
    const int g2 = BCNT * (SLEN / 256) * (VDIM / 128);
    hipLaunchKernelGGL(gemm2_k, dim3(g2), dim3(512), smem_bytes, stream, hidden, Wh, bh, out, dom);
}

// Round 5
// 538.696 us; speedup vs baseline: 1.3575x; 1.2223x over previous
//
#include <hip/hip_runtime.h>
#include <hip/hip_bf16.h>

// DomainSpecificHeads: out[b] = (hs[b] @ W_base + b_base) @ W_heads[idx[b]] + b_heads[idx[b]]
// B=8 S=512 D=1024 V=32000 ND=8 (slot ND = default head for out-of-range ids)

#define BCNT 8
#define SLEN 512
#define DDIM 1024
#define VDIM 32000
#define NDOM 8

typedef __attribute__((ext_vector_type(4))) float f32x4;
typedef __attribute__((ext_vector_type(8))) short bf16x8;

static __device__ __forceinline__ unsigned short f2bf(float f) {
    union { float f; unsigned int u; } x; x.f = f;
    unsigned int u = x.u;
    return (unsigned short)((u + 0x7FFFu + ((u >> 16) & 1u)) >> 16);  // RNE
}

// packed RNE f32x2 -> bf16x2 ; compiles to v_cvt_pk_bf16_f32 (m240: let compiler fuse)
static __device__ __forceinline__ unsigned int pack2(float lo, float hi) {
    float2 t; t.x = lo; t.y = hi;
    union { __hip_bfloat162 h; unsigned int u; } c;
    c.h = __float22bfloat162_rn(t);
    return c.u;
}

#define SBAR()   __builtin_amdgcn_s_barrier()
#define SCHED0() __builtin_amdgcn_sched_barrier(0)

// ---------------- G1: hidden = hs @ W_base + b_base  (fp32 in, bf16 out) ----------------
// 128x128 tile, BK=64, 256 threads, 2x2 waves (validated round-1 structure).
__global__ __launch_bounds__(256)
void gemm1_k(const float* __restrict__ Af, const float* __restrict__ Bbase,
             const float* __restrict__ bias, __hip_bfloat16* __restrict__ Cb,
             int Mrows)
{
    __shared__ __align__(16) __hip_bfloat16 lds_a[128 * 64];
    __shared__ __align__(16) unsigned int   lds_b[32 * 128];

    const int tid  = threadIdx.x;
    const int lane = tid & 63;
    const int w    = tid >> 6;

    const int nwg = gridDim.x;
    const int bid = blockIdx.x;
    const int q   = nwg >> 3;
    const int sid = (bid & 7) * q + (bid >> 3);

    const int MT = Mrows >> 7;
    const int mt = sid % MT;
    const int nt = sid / MT;
    const int m0 = mt << 7;
    const int n0 = nt << 7;

    f32x4 acc[4][4];
    #pragma unroll
    for (int m = 0; m < 4; ++m)
        #pragma unroll
        for (int n = 0; n < 4; ++n)
            acc[m][n] = (f32x4)0.0f;

    const int wr = w >> 1, wc = w & 1;
    const int lr = lane & 15, lg = lane >> 4;

    for (int kt = 0; kt < DDIM / 64; ++kt) {
        const int kbase = kt * 64;

        #pragma unroll
        for (int t = 0; t < 8; ++t) {
            const int flat = (t * 256 + tid) * 4;
            const int row = flat >> 6, col = flat & 63;
            const float4 v = *(const float4*)(Af + (size_t)(m0 + row) * DDIM + kbase + col);
            uint2 pp;
            pp.x = pack2(v.x, v.y);
            pp.y = pack2(v.z, v.w);
            *(uint2*)(lds_a + flat) = pp;
        }

        #pragma unroll
        for (int t = 0; t < 4; ++t) {
            const int id = t * 256 + tid;
            const int kk = id >> 5;
            const int n  = (id & 31) << 2;
            const float* b0 = Bbase + (size_t)(kbase + 2 * kk) * DDIM + n0 + n;
            const float4 e = *(const float4*)b0;
            const float4 o = *(const float4*)(b0 + DDIM);
            uint4 pw;
            pw.x = pack2(e.x, o.x);
            pw.y = pack2(e.y, o.y);
            pw.z = pack2(e.z, o.z);
            pw.w = pack2(e.w, o.w);
            const int ns = n ^ ((kk & 4) << 2);
            *(uint4*)&lds_b[kk * 128 + ns] = pw;
        }

        __syncthreads();

        #pragma unroll
        for (int ks = 0; ks < 2; ++ks) {
            bf16x8 af[4], bfr[4];
            #pragma unroll
            for (int m = 0; m < 4; ++m) {
                const int row = wr * 64 + m * 16 + lr;
                const int k   = ks * 32 + lg * 8;
                af[m] = *(const bf16x8*)&lds_a[row * 64 + k];
            }
            #pragma unroll
            for (int n = 0; n < 4; ++n) {
                const int col = wc * 64 + n * 16 + lr;
                const int kkb = ks * 16 + lg * 4;
                union { unsigned int u[4]; bf16x8 v; } cvt;
                #pragma unroll
                for (int j = 0; j < 4; ++j) {
                    const int kk = kkb + j;
                    const int ns = col ^ ((kk & 4) << 2);
                    cvt.u[j] = lds_b[kk * 128 + ns];
                }
                bfr[n] = cvt.v;
            }
            #pragma unroll
            for (int m = 0; m < 4; ++m)
                #pragma unroll
                for (int n = 0; n < 4; ++n)
                    acc[m][n] = __builtin_amdgcn_mfma_f32_16x16x32_bf16(af[m], bfr[n], acc[m][n], 0, 0, 0);
        }

        __syncthreads();
    }

    #pragma unroll
    for (int m = 0; m < 4; ++m) {
        #pragma unroll
        for (int n = 0; n < 4; ++n) {
            const int col = n0 + wc * 64 + n * 16 + lr;
            const float bv = bias[col];
            #pragma unroll
            for (int r = 0; r < 4; ++r) {
                const int row = m0 + wr * 64 + m * 16 + lg * 4 + r;
                Cb[(size_t)row * DDIM + col] = __hip_bfloat16_raw{f2bf(acc[m][n][r] + bv)};
            }
        }
    }
}

// ---------------- G2: out = hidden @ W_heads[idx] + b_heads[idx] ----------------
// m97-regime: BM=BN=128, BK=64, 256 threads (2x2 waves, 64x64 wave tiles),
// single-buffered 32 KB LDS -> 3 blocks/CU (launch_bounds(256,3)).
// Two barriers per K-step; B reg-prefetch stays in flight via counted vmcnt(8).
// CRITICAL (R4 lesson): every cluster boundary is pinned with sched_barrier(0) so
// the counted vmcnt(8) is exact — without the pins the compiler hoists the 8
// LOADB buffer-loads ahead of STAGEA's global_load_lds and vmcnt(8) no longer
// guarantees the A-tile DMA has landed (race -> absmax 1.34 in R4).
// A: global_load_lds, source pre-swizzled kbyte^=(row&7)<<4, same XOR on read.
// B: fp32 float4 loads (8 k-rows x 4 cols/thread) -> k-pair u32, [n][kk] layout,
//    quad slot kk ^ ((n>>1)&7)<<2 -> 8 quads x 8 lanes on write AND read (conflict-free).
__global__ __launch_bounds__(256, 3)
void gemm2_k(const __hip_bfloat16* __restrict__ A, const float* __restrict__ Wh,
             const float* __restrict__ bh, float* __restrict__ out,
             const int* __restrict__ dom)
{
    __shared__ __align__(16) __hip_bfloat16 ldsA[128 * 64];   // 16 KB
    __shared__ __align__(16) unsigned int   ldsB[128 * 32];   // 16 KB, [n][kk] u32 k-pairs

    const int tid  = threadIdx.x;
    const int lane = tid & 63;
    const int w    = tid >> 6;      // 0..3
    const int wr   = w >> 1;        // 0..1
    const int wc   = w & 1;         // 0..1
    const int lr   = lane & 15;
    const int lg   = lane >> 4;

    // XCD-chunked swizzle; grid = 8000 (%8==0). XCD x gets exactly example x's
    // head streamed through its L2; mt innermost -> 4 M-blocks share each W panel.
    const int bid  = blockIdx.x;
    const int q    = gridDim.x >> 3;             // 1000
    const int sid  = (bid & 7) * q + (bid >> 3);
    const int mt   = sid & 3;
    const int rest = sid >> 2;
    const int nt   = rest % 250;
    const int ex   = rest / 250;
    const int m0   = ex * SLEN + mt * 128;
    const int n0   = nt * 128;

    const int di  = dom[ex];
    const int hid = (di >= 0 && di < NDOM) ? di : NDOM;
    const float* Bp   = Wh + (size_t)hid * DDIM * (size_t)VDIM;
    const float* bias = bh + (size_t)hid * (size_t)VDIM;

    f32x4 acc[4][4];
    #pragma unroll
    for (int m = 0; m < 4; ++m)
        #pragma unroll
        for (int n = 0; n < 4; ++n)
            acc[m][n] = (f32x4)0.0f;

    // B staging: thread owns 8 k-rows x 4 cols (float4), 256 threads cover 64x128.
    const int nb4 = (tid & 31) << 2;     // col base 0..124
    const int kb  = (tid >> 5) << 3;     // k base 0..56
    const int qb  = kb >> 1;             // kk-quad slot base (multiple of 4)

    f32x4 br4[8];

    #define LOADB(KT) do {                                                         \
        const float* _p = Bp + (size_t)((KT) * 64 + kb) * VDIM + n0 + nb4;         \
        _Pragma("unroll")                                                          \
        for (int j = 0; j < 8; ++j) br4[j] = *(const f32x4*)(_p + (size_t)j * VDIM); \
    } while (0)

    #define WRITEB() do {                                                          \
        _Pragma("unroll")                                                          \
        for (int i = 0; i < 4; ++i) {                                              \
            const int col  = nb4 + i;                                              \
            const int slot = qb ^ (((col >> 1) & 7) << 2);                         \
            uint4 wv;                                                              \
            wv.x = pack2(br4[0][i], br4[1][i]);                                    \
            wv.y = pack2(br4[2][i], br4[3][i]);                                    \
            wv.z = pack2(br4[4][i], br4[5][i]);                                    \
            wv.w = pack2(br4[6][i], br4[7][i]);                                    \
            *(uint4*)&ldsB[col * 32 + slot] = wv;                                  \
        }                                                                          \
    } while (0)

    #define STAGEA(KT) do {                                                        \
        _Pragma("unroll")                                                          \
        for (int i = 0; i < 4; ++i) {                                              \
            const int base_e = (i * 4 + w) * 512;                                  \
            const int flat   = base_e + lane * 8;                                  \
            const int row    = flat >> 6;                                          \
            const int kbyte  = (flat & 63) * 2;                                    \
            const int srck   = (kbyte ^ ((row & 7) << 4)) >> 1;                    \
            const __hip_bfloat16* src = A + (size_t)(m0 + row) * DDIM + (KT) * 64 + srck; \
            __builtin_amdgcn_global_load_lds(                                      \
                (const __attribute__((address_space(1))) unsigned int*)src,        \
                (__attribute__((address_space(3))) unsigned int*)(ldsA + base_e),  \
                16, 0, 0);                                                         \
        }                                                                          \
    } while (0)

    #define COMPUTE() do {                                                         \
        _Pragma("unroll")                                                          \
        for (int ks = 0; ks < 2; ++ks) {                                           \
            bf16x8 af[4], bfr[4];                                                  \
            _Pragma("unroll")                                                      \
            for (int m = 0; m < 4; ++m) {                                          \
                const int row = wr * 64 + m * 16 + lr;                             \
                const int kby = ks * 64 + lg * 16;                                 \
                const int eff = kby ^ ((row & 7) << 4);                            \
                af[m] = *(const bf16x8*)&ldsA[row * 64 + (eff >> 1)];              \
            }                                                                      \
            _Pragma("unroll")                                                      \
            for (int n = 0; n < 4; ++n) {                                          \
                const int col  = wc * 64 + n * 16 + lr;                            \
                const int kkb  = ks * 16 + lg * 4;                                 \
                const int slot = kkb ^ (((col >> 1) & 7) << 2);                    \
                bfr[n] = *(const bf16x8*)&ldsB[col * 32 + slot];                   \
            }                                                                      \
            _Pragma("unroll")                                                      \
            for (int m = 0; m < 4; ++m)                                            \
                _Pragma("unroll")                                                  \
                for (int n = 0; n < 4; ++n)                                        \
                    acc[m][n] = __builtin_amdgcn_mfma_f32_16x16x32_bf16(af[m], bfr[n], acc[m][n], 0, 0, 0); \
        }                                                                          \
    } while (0)

    // ---- prologue (order pinned: LOADB(0) | STAGEA(0) | WRITEB | LOADB(1) | wait) ----
    LOADB(0);
    SCHED0();
    STAGEA(0);
    SCHED0();
    WRITEB();                 // compiler-inserted vmcnt drains LOADB(0)'s 8
    SCHED0();
    LOADB(1);                 // stays in flight across compute
    SCHED0();
    asm volatile("s_waitcnt vmcnt(8) lgkmcnt(0)" ::: "memory");  // drains STAGEA(0)'s 4 gll + LDS writes
    SCHED0();
    SBAR();

    // ---- main loop: compute(kt) -> barrier -> stage(kt+1) -> wait -> barrier ----
    for (int kt = 0; kt < 16; ++kt) {
        COMPUTE();
        if (kt < 15) {
            SCHED0();
            SBAR();                       // all waves done reading LDS
            SCHED0();
            STAGEA(kt + 1);               // 4x global_load_lds (oldest vmem from here on)
            SCHED0();
            WRITEB();                     // br4 holds B(kt+1); compiler drains its 8 loads
            SCHED0();
            if (kt < 14) {
                LOADB(kt + 2);            // 8 loads fly across next compute
                SCHED0();
                asm volatile("s_waitcnt vmcnt(8) lgkmcnt(0)" ::: "memory");
            } else {
                asm volatile("s_waitcnt vmcnt(0) lgkmcnt(0)" ::: "memory");
            }
            SCHED0();
            SBAR();
        }
    }

    // ---- epilogue ----
    #pragma unroll
    for (int n = 0; n < 4; ++n) {
        const int col = n0 + wc * 64 + n * 16 + lr;
        const float bv = bias[col];
        #pragma unroll
        for (int m = 0; m < 4; ++m) {
            #pragma unroll
            for (int r = 0; r < 4; ++r) {
                const int row = m0 + wr * 64 + m * 16 + lg * 4 + r;
                out[(size_t)row * VDIM + col] = acc[m][n][r] + bv;
            }
        }
    }

    #undef LOADB
    #undef WRITEB
    #undef STAGEA
    #undef COMPUTE
}

extern "C" void kernel_launch(void* const* d_in, const int* in_sizes, int n_in,
                              void* d_out, int out_size, void* d_ws, size_t ws_size,
                              hipStream_t stream)
{
    const float* hs  = (const float*)d_in[0];   // [8,512,1024] fp32
    const int*   dom = (const int*)d_in[1];     // [8] int32
    const float* Wb  = (const float*)d_in[2];   // [1024,1024] fp32
    const float* bb  = (const float*)d_in[3];   // [1024] fp32
    const float* Wh  = (const float*)d_in[4];   // [9,1024,32000] fp32
    const float* bh  = (const float*)d_in[5];   // [9,32000] fp32
    float* out = (float*)d_out;                 // [8,512,32000] fp32
    __hip_bfloat16* hidden = (__hip_bfloat16*)d_ws;   // [4096,1024] bf16, 8 MB

    const int M = BCNT * SLEN;  // 4096

    // G1: 256 blocks of 256 threads
    const int g1 = (M / 128) * (DDIM / 128);
    hipLaunchKernelGGL(gemm1_k, dim3(g1), dim3(256), 0, stream, hs, Wb, bb, hidden, M);

    // G2: 8 ex * 4 mt * 250 nt = 8000 blocks of 256 threads
    const int g2 = BCNT * (SLEN / 128) * (VDIM / 128);
    hipLaunchKernelGGL(gemm2_k, dim3(g2), dim3(256), 0, stream, hidden, Wh, bh, out, dom);
}

// Round 7
// 531.416 us; speedup vs baseline: 1.3761x; 1.0137x over previous
//
#include <hip/hip_runtime.h>
#include <hip/hip_bf16.h>

// DomainSpecificHeads: out[b] = (hs[b] @ W_base + b_base) @ W_heads[idx[b]] + b_heads[idx[b]]
// B=8 S=512 D=1024 V=32000 ND=8 (slot ND = default head for out-of-range ids)

#define BCNT 8
#define SLEN 512
#define DDIM 1024
#define VDIM 32000
#define NDOM 8

typedef __attribute__((ext_vector_type(4))) float f32x4;
typedef __attribute__((ext_vector_type(8))) short bf16x8;

static __device__ __forceinline__ unsigned short f2bf(float f) {
    union { float f; unsigned int u; } x; x.f = f;
    unsigned int u = x.u;
    return (unsigned short)((u + 0x7FFFu + ((u >> 16) & 1u)) >> 16);  // RNE
}

// packed RNE f32x2 -> bf16x2 ; compiles to v_cvt_pk_bf16_f32 (m240: let compiler fuse)
static __device__ __forceinline__ unsigned int pack2(float lo, float hi) {
    float2 t; t.x = lo; t.y = hi;
    union { __hip_bfloat162 h; unsigned int u; } c;
    c.h = __float22bfloat162_rn(t);
    return c.u;
}

#define SBAR()   __builtin_amdgcn_s_barrier()
#define SCHED0() __builtin_amdgcn_sched_barrier(0)

// ---------------- G1: hidden = hs @ W_base + b_base  (fp32 in, bf16 out) ----------------
// 128x128 tile, BK=64, 256 threads, 2x2 waves (validated round-1 structure).
__global__ __launch_bounds__(256)
void gemm1_k(const float* __restrict__ Af, const float* __restrict__ Bbase,
             const float* __restrict__ bias, __hip_bfloat16* __restrict__ Cb,
             int Mrows)
{
    __shared__ __align__(16) __hip_bfloat16 lds_a[128 * 64];
    __shared__ __align__(16) unsigned int   lds_b[32 * 128];

    const int tid  = threadIdx.x;
    const int lane = tid & 63;
    const int w    = tid >> 6;

    const int nwg = gridDim.x;
    const int bid = blockIdx.x;
    const int q   = nwg >> 3;
    const int sid = (bid & 7) * q + (bid >> 3);

    const int MT = Mrows >> 7;
    const int mt = sid % MT;
    const int nt = sid / MT;
    const int m0 = mt << 7;
    const int n0 = nt << 7;

    f32x4 acc[4][4];
    #pragma unroll
    for (int m = 0; m < 4; ++m)
        #pragma unroll
        for (int n = 0; n < 4; ++n)
            acc[m][n] = (f32x4)0.0f;

    const int wr = w >> 1, wc = w & 1;
    const int lr = lane & 15, lg = lane >> 4;

    for (int kt = 0; kt < DDIM / 64; ++kt) {
        const int kbase = kt * 64;

        #pragma unroll
        for (int t = 0; t < 8; ++t) {
            const int flat = (t * 256 + tid) * 4;
            const int row = flat >> 6, col = flat & 63;
            const float4 v = *(const float4*)(Af + (size_t)(m0 + row) * DDIM + kbase + col);
            uint2 pp;
            pp.x = pack2(v.x, v.y);
            pp.y = pack2(v.z, v.w);
            *(uint2*)(lds_a + flat) = pp;
        }

        #pragma unroll
        for (int t = 0; t < 4; ++t) {
            const int id = t * 256 + tid;
            const int kk = id >> 5;
            const int n  = (id & 31) << 2;
            const float* b0 = Bbase + (size_t)(kbase + 2 * kk) * DDIM + n0 + n;
            const float4 e = *(const float4*)b0;
            const float4 o = *(const float4*)(b0 + DDIM);
            uint4 pw;
            pw.x = pack2(e.x, o.x);
            pw.y = pack2(e.y, o.y);
            pw.z = pack2(e.z, o.z);
            pw.w = pack2(e.w, o.w);
            const int ns = n ^ ((kk & 4) << 2);
            *(uint4*)&lds_b[kk * 128 + ns] = pw;
        }

        __syncthreads();

        #pragma unroll
        for (int ks = 0; ks < 2; ++ks) {
            bf16x8 af[4], bfr[4];
            #pragma unroll
            for (int m = 0; m < 4; ++m) {
                const int row = wr * 64 + m * 16 + lr;
                const int k   = ks * 32 + lg * 8;
                af[m] = *(const bf16x8*)&lds_a[row * 64 + k];
            }
            #pragma unroll
            for (int n = 0; n < 4; ++n) {
                const int col = wc * 64 + n * 16 + lr;
                const int kkb = ks * 16 + lg * 4;
                union { unsigned int u[4]; bf16x8 v; } cvt;
                #pragma unroll
                for (int j = 0; j < 4; ++j) {
                    const int kk = kkb + j;
                    const int ns = col ^ ((kk & 4) << 2);
                    cvt.u[j] = lds_b[kk * 128 + ns];
                }
                bfr[n] = cvt.v;
            }
            #pragma unroll
            for (int m = 0; m < 4; ++m)
                #pragma unroll
                for (int n = 0; n < 4; ++n)
                    acc[m][n] = __builtin_amdgcn_mfma_f32_16x16x32_bf16(af[m], bfr[n], acc[m][n], 0, 0, 0);
        }

        __syncthreads();
    }

    #pragma unroll
    for (int m = 0; m < 4; ++m) {
        #pragma unroll
        for (int n = 0; n < 4; ++n) {
            const int col = n0 + wc * 64 + n * 16 + lr;
            const float bv = bias[col];
            #pragma unroll
            for (int r = 0; r < 4; ++r) {
                const int row = m0 + wr * 64 + m * 16 + lg * 4 + r;
                Cb[(size_t)row * DDIM + col] = __hip_bfloat16_raw{f2bf(acc[m][n][r] + bv)};
            }
        }
    }
}

// ---------------- G2: out = hidden @ W_heads[idx] + b_heads[idx] ----------------
// BM=256 BN=128 BK=64, 512 threads (8 waves, 4x2 grid of 64x64 wave tiles),
// single-buffered 48 KB LDS -> 2 blocks/CU (launch_bounds(512,4), 16 waves/CU).
// Sync skeleton IDENTICAL to the R3/R5-validated schedule (same cluster order,
// same SCHED0 pins, same vmcnt counts): STAGEA = 4 global_load_lds per wave,
// LOADB = 8 loads per thread, WRITEB drains B-loads via compiler vmcnt,
// explicit vmcnt(8) leaves exactly the 8 prefetched B-loads in flight.
// R4 lesson: the SCHED0 pins at cluster boundaries are what make vmcnt(8) exact.
// A: global_load_lds, source pre-swizzled kbyte^=(row&7)<<4, same XOR on read.
// B: fp32 float2 loads (8 k-rows x 2 cols/thread) -> k-pair u32, [n][kk] layout,
//    quad slot (kb>>1) ^ ((n>>1)&7)<<2 -> conflict-free floor on write AND read.
__global__ __launch_bounds__(512, 4)
void gemm2_k(const __hip_bfloat16* __restrict__ A, const float* __restrict__ Wh,
             const float* __restrict__ bh, float* __restrict__ out,
             const int* __restrict__ dom)
{
    __shared__ __align__(16) __hip_bfloat16 ldsA[256 * 64];   // 32 KB
    __shared__ __align__(16) unsigned int   ldsB[128 * 32];   // 16 KB, [n][kk] u32 k-pairs

    const int tid  = threadIdx.x;
    const int lane = tid & 63;
    const int w    = tid >> 6;      // 0..7
    const int wr   = w >> 1;        // 0..3 -> 64-row stripe
    const int wc   = w & 1;         // 0..1 -> 64-col stripe
    const int lr   = lane & 15;
    const int lg   = lane >> 4;

    // XCD-chunked swizzle; grid = 4000 (%8==0). Each XCD gets 500 consecutive sids
    // = exactly one example's full panel set; mt innermost -> 2 M-blocks per panel.
    const int bid  = blockIdx.x;
    const int q    = gridDim.x >> 3;             // 500
    const int sid  = (bid & 7) * q + (bid >> 3);
    const int mt   = sid & 1;
    const int rest = sid >> 1;
    const int nt   = rest % 250;
    const int ex   = rest / 250;
    const int m0   = ex * SLEN + mt * 256;
    const int n0   = nt * 128;

    const int di  = dom[ex];
    const int hid = (di >= 0 && di < NDOM) ? di : NDOM;
    const float* Bp   = Wh + (size_t)hid * DDIM * (size_t)VDIM;
    const float* bias = bh + (size_t)hid * (size_t)VDIM;

    f32x4 acc[4][4];
    #pragma unroll
    for (int m = 0; m < 4; ++m)
        #pragma unroll
        for (int n = 0; n < 4; ++n)
            acc[m][n] = (f32x4)0.0f;

    // B staging: thread owns 8 k-rows x 2 cols (float2); 512 threads cover 64x128.
    const int nb  = (tid & 63) << 1;     // col base 0..126 (even)
    const int kb  = (tid >> 6) << 3;     // k base 0..56 (8 rows per wave)
    const int qb  = kb >> 1;             // kk-quad slot base (multiple of 4)
    const int bsw = (lane & 7) << 2;     // == ((nb>>1)&7)<<2
    const int bslot = qb ^ bsw;

    float2 br[8];

    #define LOADB(KT) do {                                                         \
        const float* _p = Bp + (size_t)((KT) * 64 + kb) * VDIM + n0 + nb;          \
        _Pragma("unroll")                                                          \
        for (int j = 0; j < 8; ++j) br[j] = *(const float2*)(_p + (size_t)j * VDIM); \
    } while (0)

    #define WRITEB() do {                                                          \
        uint4 w0, w1;                                                              \
        w0.x = pack2(br[0].x, br[1].x); w0.y = pack2(br[2].x, br[3].x);            \
        w0.z = pack2(br[4].x, br[5].x); w0.w = pack2(br[6].x, br[7].x);            \
        w1.x = pack2(br[0].y, br[1].y); w1.y = pack2(br[2].y, br[3].y);            \
        w1.z = pack2(br[4].y, br[5].y); w1.w = pack2(br[6].y, br[7].y);            \
        *(uint4*)&ldsB[nb * 32 + bslot]       = w0;                                \
        *(uint4*)&ldsB[(nb + 1) * 32 + bslot] = w1;                                \
    } while (0)

    #define STAGEA(KT) do {                                                        \
        _Pragma("unroll")                                                          \
        for (int i = 0; i < 4; ++i) {                                              \
            const int base_e = (i * 8 + w) * 512;                                  \
            const int flat   = base_e + lane * 8;                                  \
            const int row    = flat >> 6;                                          \
            const int kbyte  = (flat & 63) * 2;                                    \
            const int srck   = (kbyte ^ ((row & 7) << 4)) >> 1;                    \
            const __hip_bfloat16* src = A + (size_t)(m0 + row) * DDIM + (KT) * 64 + srck; \
            __builtin_amdgcn_global_load_lds(                                      \
                (const __attribute__((address_space(1))) unsigned int*)src,        \
                (__attribute__((address_space(3))) unsigned int*)(ldsA + base_e),  \
                16, 0, 0);                                                         \
        }                                                                          \
    } while (0)

    #define COMPUTE() do {                                                         \
        _Pragma("unroll")                                                          \
        for (int ks = 0; ks < 2; ++ks) {                                           \
            bf16x8 af[4], bfr[4];                                                  \
            _Pragma("unroll")                                                      \
            for (int m = 0; m < 4; ++m) {                                          \
                const int row = wr * 64 + m * 16 + lr;                             \
                const int kby = ks * 64 + lg * 16;                                 \
                const int eff = kby ^ ((row & 7) << 4);                            \
                af[m] = *(const bf16x8*)&ldsA[row * 64 + (eff >> 1)];              \
            }                                                                      \
            _Pragma("unroll")                                                      \
            for (int n = 0; n < 4; ++n) {                                          \
                const int col  = wc * 64 + n * 16 + lr;                            \
                const int kkb  = ks * 16 + lg * 4;                                 \
                const int slot = kkb ^ (((col >> 1) & 7) << 2);                    \
                bfr[n] = *(const bf16x8*)&ldsB[col * 32 + slot];                   \
            }                                                                      \
            _Pragma("unroll")                                                      \
            for (int m = 0; m < 4; ++m)                                            \
                _Pragma("unroll")                                                  \
                for (int n = 0; n < 4; ++n)                                        \
                    acc[m][n] = __builtin_amdgcn_mfma_f32_16x16x32_bf16(af[m], bfr[n], acc[m][n], 0, 0, 0); \
        }                                                                          \
    } while (0)

    // ---- prologue (order pinned: LOADB(0) | STAGEA(0) | WRITEB | LOADB(1) | wait) ----
    LOADB(0);
    SCHED0();
    STAGEA(0);
    SCHED0();
    WRITEB();                 // compiler-inserted vmcnt drains LOADB(0)'s 8
    SCHED0();
    LOADB(1);                 // stays in flight across compute
    SCHED0();
    asm volatile("s_waitcnt vmcnt(8) lgkmcnt(0)" ::: "memory");  // drains STAGEA(0)'s 4 gll + LDS writes
    SCHED0();
    SBAR();

    // ---- main loop: compute(kt) -> barrier -> stage(kt+1) -> wait -> barrier ----
    for (int kt = 0; kt < 16; ++kt) {
        COMPUTE();
        if (kt < 15) {
            SCHED0();
            SBAR();                       // all waves done reading LDS
            SCHED0();
            STAGEA(kt + 1);               // 4x global_load_lds per wave
            SCHED0();
            WRITEB();                     // br holds B(kt+1); compiler drains its 8 loads
            SCHED0();
            if (kt < 14) {
                LOADB(kt + 2);            // 8 loads fly across next compute
                SCHED0();
                asm volatile("s_waitcnt vmcnt(8) lgkmcnt(0)" ::: "memory");
            } else {
                asm volatile("s_waitcnt vmcnt(0) lgkmcnt(0)" ::: "memory");
            }
            SCHED0();
            SBAR();
        }
    }

    // ---- epilogue ----
    #pragma unroll
    for (int n = 0; n < 4; ++n) {
        const int col = n0 + wc * 64 + n * 16 + lr;
        const float bv = bias[col];
        #pragma unroll
        for (int m = 0; m < 4; ++m) {
            #pragma unroll
            for (int r = 0; r < 4; ++r) {
                const int row = m0 + wr * 64 + m * 16 + lg * 4 + r;
                out[(size_t)row * VDIM + col] = acc[m][n][r] + bv;
            }
        }
    }

    #undef LOADB
    #undef WRITEB
    #undef STAGEA
    #undef COMPUTE
}

extern "C" void kernel_launch(void* const* d_in, const int* in_sizes, int n_in,
                              void* d_out, int out_size, void* d_ws, size_t ws_size,
                              hipStream_t stream)
{
    const float* hs  = (const float*)d_in[0];   // [8,512,1024] fp32
    const int*   dom = (const int*)d_in[1];     // [8] int32
    const float* Wb  = (const float*)d_in[2];   // [1024,1024] fp32
    const float* bb  = (const float*)d_in[3];   // [1024] fp32
    const float* Wh  = (const float*)d_in[4];   // [9,1024,32000] fp32
    const float* bh  = (const float*)d_in[5];   // [9,32000] fp32
    float* out = (float*)d_out;                 // [8,512,32000] fp32
    __hip_bfloat16* hidden = (__hip_bfloat16*)d_ws;   // [4096,1024] bf16, 8 MB

    const int M = BCNT * SLEN;  // 4096

    // G1: 256 blocks of 256 threads
    const int g1 = (M / 128) * (DDIM / 128);
    hipLaunchKernelGGL(gemm1_k, dim3(g1), dim3(256), 0, stream, hs, Wb, bb, hidden, M);

    // G2: 8 ex * 2 mt * 250 nt = 4000 blocks of 512 threads
    const int g2 = BCNT * (SLEN / 256) * (VDIM / 128);
    hipLaunchKernelGGL(gemm2_k, dim3(g2), dim3(512), 0, stream, hidden, Wh, bh, out, dom);
}